// Round 9
// baseline (11204.638 us; speedup 1.0000x reference)
//
#include <hip/hip_runtime.h>
#include <hip/hip_cooperative_groups.h>
#include <stdint.h>

namespace cg = cooperative_groups;

#define B_    4096
#define H_    1024
#define T_    60
#define IN_   1028
#define KA_   1056      // IN_ padded to multiple of 32
#define G4_   4096      // 4*H
#define MLPH_ 64

typedef __attribute__((ext_vector_type(8))) short bf16x8;
typedef __attribute__((ext_vector_type(4))) float f32x4;
typedef __attribute__((ext_vector_type(4))) unsigned short u16x4;

#define GLOBAL_AS __attribute__((address_space(1)))
#define LDS_AS    __attribute__((address_space(3)))

__device__ __forceinline__ void gload_lds16(const void* g, void* l) {
  __builtin_amdgcn_global_load_lds((GLOBAL_AS void*)const_cast<void*>(g),
                                   (LDS_AS void*)l, 16, 0, 0);
}

__device__ __forceinline__ unsigned short f2bf(float f) {
  union { float f; unsigned int u; } v; v.f = f;
  unsigned int r = v.u + 0x7FFFu + ((v.u >> 16) & 1u);
  return (unsigned short)(r >> 16);
}

__device__ __forceinline__ float bf2f(unsigned short u) {
  union { unsigned int u; float f; } v; v.u = ((unsigned int)u) << 16;
  return v.f;
}

__device__ __forceinline__ float sigmf(float x) {
  float e = __expf(-x);
  return __builtin_amdgcn_rcpf(1.0f + e);
}

__device__ __forceinline__ float tanh_fast(float x) {
  x = fminf(fmaxf(x, -15.0f), 15.0f);
  float e = __expf(2.0f * x);
  return (e - 1.0f) * __builtin_amdgcn_rcpf(e + 1.0f);
}

// ---------------- conversion / setup kernels ----------------

__global__ void k_conv_bf16(const float* __restrict__ src,
                            unsigned short* __restrict__ dst, int n) {
  int i = blockIdx.x * blockDim.x + threadIdx.x;
  int stride = gridDim.x * blockDim.x;
  for (; i < n; i += stride) dst[i] = f2bf(src[i]);
}

__global__ void k_conv_wih(const float* __restrict__ w,
                           unsigned short* __restrict__ dst) {
  int i = blockIdx.x * blockDim.x + threadIdx.x;
  int stride = gridDim.x * blockDim.x;
  const int n = G4_ * KA_;
  for (; i < n; i += stride) {
    int r = i / KA_, k = i - r * KA_;
    dst[i] = (k < IN_) ? f2bf(w[(size_t)r * IN_ + k]) : (unsigned short)0;
  }
}

__global__ void k_build_zaug(const float* __restrict__ z,
                             const float* __restrict__ lp,
                             const float* __restrict__ lv,
                             unsigned short* __restrict__ dst) {
  int i = blockIdx.x * blockDim.x + threadIdx.x;
  int stride = gridDim.x * blockDim.x;
  const int n = B_ * KA_;
  for (; i < n; i += stride) {
    int b = i / KA_, k = i - b * KA_;
    float v;
    if (k < H_)            v = z[(size_t)b * H_ + k];
    else if (k < H_ + 2)   v = lp[b * 2 + (k - H_)];
    else if (k < IN_)      v = lv[b * 2 + (k - H_ - 2)];
    else                   v = 0.0f;
    dst[i] = f2bf(v);
  }
}

// ================= persistent cooperative LSTM =================
// 256 blocks (1/CU) x 512 threads, 128 KB LDS. Block = 256 rows x 64 hc x 4
// gates; 8 waves (wm=wave>>2 in {0,1} -> 128 rows, wn=wave&3 -> 16 hc).
// xg kept in registers (32 u16x4/lane); c in LDS (64 KB); h ping-pong global.
// Per step: GEMM vs W_hh (2-buf LDS, 1 barrier/tile; round-4-proven swizzle:
// phys slot s of row r holds global chunk s ^ ((r>>1)&3), staged via
// pre-swizzled global source) -> fused cell update -> h store -> fence ->
// grid.sync -> inline MLP (16 rows/block) -> delta.

__global__ __launch_bounds__(512, 2) void k_persist(
    const unsigned short* __restrict__ zaug, const unsigned short* __restrict__ wih,
    const unsigned short* __restrict__ whh, const unsigned short* __restrict__ w1,
    const float* __restrict__ bih, const float* __restrict__ bhh,
    const float* __restrict__ b1, const float* __restrict__ w2,
    const float* __restrict__ b2,
    unsigned short* h_a, unsigned short* h_b,
    float* __restrict__ delta) {
  __shared__ char smem[131072];
  unsigned short* As = (unsigned short*)smem;             // 2 bufs x 16 KB
  unsigned short* Bs = (unsigned short*)(smem + 32768);   // 2 bufs x 16 KB
  float* cS  = (float*)(smem + 65536);                    // 64 KB c state
  float* hid = (float*)smem;                              // MLP overlay (4 KB)

  const int tid = threadIdx.x, lane = tid & 63, wave = tid >> 6;
  const int wm = wave >> 2, wn = wave & 3;
  const int cl = lane & 15, sl16 = lane >> 4;
  const int bId = blockIdx.x;
  const int by = (bId & 7) * 2 + ((bId >> 3) & 1);   // XCD-pinned hc-tile [0,16)
  const int bx = bId >> 4;                           // row-tile [0,16)

  const int q = tid >> 2;                                  // staging row in 128
  const int s16   = ((tid & 3) ^ ((tid >> 3) & 3)) * 16;   // pre-swizzled src slot
  const int slot8 = (sl16 ^ ((cl >> 1) & 3)) * 8;          // frag read slot (elems)
  const int hcl = wn * 16 + cl;
  const int hc  = by * 64 + hcl;

  for (int i = tid; i < 16384; i += 512) cS[i] = 0.0f;

  float bias[4];
#pragma unroll
  for (int g = 0; g < 4; ++g) bias[g] = bih[g * H_ + hc] + bhh[g * H_ + hc];

  f32x4 acc[4][8];
  bf16x8 afr[4], bfr[4];

  auto gemm = [&](const char* asrc, size_t astr, const char* bsrc, size_t bstr, int nt) {
    const char* ap  = asrc + (size_t)(bx * 256 + q) * astr + s16;
    const char* bp0 = bsrc + (size_t)((q >> 6) * H_ + by * 64 + (q & 63)) * bstr + s16;
    const char* bp1 = bsrc + (size_t)((2 + (q >> 6)) * H_ + by * 64 + (q & 63)) * bstr + s16;
    auto stage = [&](int kt, int bs) {
      gload_lds16(ap + (size_t)kt * 64,              (char*)As + bs * 16384 + tid * 16);
      gload_lds16(ap + 128 * astr + (size_t)kt * 64, (char*)As + bs * 16384 + 8192 + tid * 16);
      gload_lds16(bp0 + (size_t)kt * 64,             (char*)Bs + bs * 16384 + tid * 16);
      gload_lds16(bp1 + (size_t)kt * 64,             (char*)Bs + bs * 16384 + 8192 + tid * 16);
    };
    stage(0, 0);
    __syncthreads();
    for (int kt = 0; kt < nt; ++kt) {
      const int cur = kt & 1;
      if (kt + 1 < nt) stage(kt + 1, cur ^ 1);
      const unsigned short* Ab = As + cur * 8192;
      const unsigned short* Bb = Bs + cur * 8192;
#pragma unroll
      for (int g = 0; g < 4; ++g)
        bfr[g] = *(const bf16x8*)&Bb[(g * 64 + hcl) * 32 + slot8];
#pragma unroll
      for (int m = 0; m < 4; ++m)
        afr[m] = *(const bf16x8*)&Ab[(wm * 128 + m * 16 + cl) * 32 + slot8];
#pragma unroll
      for (int g = 0; g < 4; ++g)
#pragma unroll
        for (int m = 0; m < 4; ++m)
          acc[g][m] = __builtin_amdgcn_mfma_f32_16x16x32_bf16(afr[m], bfr[g], acc[g][m], 0, 0, 0);
#pragma unroll
      for (int m = 0; m < 4; ++m)
        afr[m] = *(const bf16x8*)&Ab[(wm * 128 + (4 + m) * 16 + cl) * 32 + slot8];
#pragma unroll
      for (int g = 0; g < 4; ++g)
#pragma unroll
        for (int m = 0; m < 4; ++m)
          acc[g][4 + m] = __builtin_amdgcn_mfma_f32_16x16x32_bf16(afr[m], bfr[g], acc[g][4 + m], 0, 0, 0);
      __syncthreads();
    }
  };

  // ---- xg phase: x_gates tile -> registers ----
#pragma unroll
  for (int g = 0; g < 4; ++g)
#pragma unroll
    for (int m = 0; m < 8; ++m) acc[g][m] = {0.f, 0.f, 0.f, 0.f};
  gemm((const char*)zaug, (size_t)KA_ * 2, (const char*)wih, (size_t)KA_ * 2, KA_ / 32);

  u16x4 xgr[8][4];
#pragma unroll
  for (int m = 0; m < 8; ++m)
#pragma unroll
    for (int j = 0; j < 4; ++j)
      xgr[m][j] = u16x4{f2bf(acc[0][m][j] + bias[0]), f2bf(acc[1][m][j] + bias[1]),
                        f2bf(acc[2][m][j] + bias[2]), f2bf(acc[3][m][j] + bias[3])};

  cg::grid_group grid = cg::this_grid();

  for (int t = 0; t < T_; ++t) {
    const unsigned short* hp = (t & 1) ? h_b : h_a;
    unsigned short*       hw = (t & 1) ? h_a : h_b;

#pragma unroll
    for (int g = 0; g < 4; ++g)
#pragma unroll
      for (int m = 0; m < 8; ++m) acc[g][m] = {0.f, 0.f, 0.f, 0.f};
    gemm((const char*)hp, (size_t)H_ * 2, (const char*)whh, (size_t)H_ * 2, H_ / 32);

    // fused cell update: c in LDS (swizzled), h -> global
#pragma unroll
    for (int m = 0; m < 8; ++m)
#pragma unroll
      for (int j = 0; j < 4; ++j) {
        int erowl = wm * 128 + m * 16 + sl16 * 4 + j;
        int cidx  = erowl * 64 + (hcl ^ ((erowl & 7) << 3));
        u16x4 xv = xgr[m][j];
        float iv = sigmf(acc[0][m][j] + bf2f(xv[0]));
        float fv = sigmf(acc[1][m][j] + bf2f(xv[1]));
        float gv = tanh_fast(acc[2][m][j] + bf2f(xv[2]));
        float ov = sigmf(acc[3][m][j] + bf2f(xv[3]));
        float cv = fv * cS[cidx] + iv * gv;
        cS[cidx] = cv;
        hw[(size_t)(bx * 256 + erowl) * H_ + hc] = f2bf(ov * tanh_fast(cv));
      }

    __threadfence();
    grid.sync();
    __threadfence();

    // ---- inline MLP: rows bId*16 .. +16; waves 0-3 compute 16 units each ----
    {
      f32x4 macc = {0.f, 0.f, 0.f, 0.f};
      const char* ha = (const char*)hw + (size_t)(bId * 16 + cl) * 2048 + sl16 * 16;
      const char* wb = (const char*)w1 + (size_t)((wave & 3) * 16 + cl) * 2048 + sl16 * 16;
      if (wave < 4) {
#pragma unroll 8
        for (int kt = 0; kt < H_ / 32; ++kt) {
          bf16x8 av = *(const bf16x8*)(ha + (size_t)kt * 64);
          bf16x8 bv = *(const bf16x8*)(wb + (size_t)kt * 64);
          macc = __builtin_amdgcn_mfma_f32_16x16x32_bf16(av, bv, macc, 0, 0, 0);
        }
      }
      __syncthreads();
      if (wave < 4) {
        float b1v = b1[wave * 16 + cl];
#pragma unroll
        for (int j = 0; j < 4; ++j)
          hid[(sl16 * 4 + j) * 64 + wave * 16 + cl] = fmaxf(macc[j] + b1v, 0.0f);
      }
      __syncthreads();
      if (tid < 32) {
        int r = tid >> 1, d = tid & 1;
        float s = b2[d];
#pragma unroll 16
        for (int k = 0; k < 64; ++k) s += hid[r * 64 + k] * w2[d * 64 + k];
        delta[((size_t)(bId * 16 + r) * T_ + t) * 2 + d] = s;
      }
      __syncthreads();
    }
  }
}

// ================= fallback path (round-4 validated) =================

__global__ __launch_bounds__(256, 4) void k_xgates(
    const unsigned short* __restrict__ zaug, const unsigned short* __restrict__ wih,
    const float* __restrict__ bih, const float* __restrict__ bhh,
    u16x4* __restrict__ xg4) {
  __shared__ unsigned short As[2][128 * 32];
  __shared__ unsigned short Bs[2][128 * 32];
  const int tid = threadIdx.x, lane = tid & 63, wave = tid >> 6;
  const int bx = blockIdx.x, by = blockIdx.y;
  const int wm = wave >> 1, wn = wave & 1;
  const int rs = lane >> 2;
  const int c16 = (((lane & 3) ^ ((lane >> 3) & 3))) * 16;
  const int rdslot = ((lane >> 4) ^ ((lane >> 1) & 3)) * 8;

  const char* asrc0 = (const char*)zaug + ((size_t)(bx * 128 + (wave * 2 + 0) * 16 + rs) * KA_) * 2 + c16;
  const char* asrc1 = (const char*)zaug + ((size_t)(bx * 128 + (wave * 2 + 1) * 16 + rs) * KA_) * 2 + c16;
  const char* bsrc0 = (const char*)wih  + ((size_t)(wave * H_ + by * 32 +  0 + rs) * KA_) * 2 + c16;
  const char* bsrc1 = (const char*)wih  + ((size_t)(wave * H_ + by * 32 + 16 + rs) * KA_) * 2 + c16;

  f32x4 acc[4][4];
#pragma unroll
  for (int g = 0; g < 4; ++g)
#pragma unroll
    for (int m = 0; m < 4; ++m) acc[g][m] = {0.f, 0.f, 0.f, 0.f};

  gload_lds16(asrc0, &As[0][(wave * 2 + 0) * 512]);
  gload_lds16(asrc1, &As[0][(wave * 2 + 1) * 512]);
  gload_lds16(bsrc0, &Bs[0][(wave * 2 + 0) * 512]);
  gload_lds16(bsrc1, &Bs[0][(wave * 2 + 1) * 512]);
  __syncthreads();

  const int nt = KA_ / 32;
  int cur = 0;
  for (int kk = 0; kk < nt; ++kk) {
    if (kk + 1 < nt) {
      const size_t kb = (size_t)(kk + 1) * 64;
      gload_lds16(asrc0 + kb, &As[cur ^ 1][(wave * 2 + 0) * 512]);
      gload_lds16(asrc1 + kb, &As[cur ^ 1][(wave * 2 + 1) * 512]);
      gload_lds16(bsrc0 + kb, &Bs[cur ^ 1][(wave * 2 + 0) * 512]);
      gload_lds16(bsrc1 + kb, &Bs[cur ^ 1][(wave * 2 + 1) * 512]);
    }
    bf16x8 a[4], b[4];
#pragma unroll
    for (int m = 0; m < 4; ++m)
      a[m] = *(const bf16x8*)&As[cur][(wm * 64 + m * 16 + (lane & 15)) * 32 + rdslot];
#pragma unroll
    for (int g = 0; g < 4; ++g)
      b[g] = *(const bf16x8*)&Bs[cur][((g * 2 + wn) * 16 + (lane & 15)) * 32 + rdslot];
#pragma unroll
    for (int g = 0; g < 4; ++g)
#pragma unroll
      for (int m = 0; m < 4; ++m)
        acc[g][m] = __builtin_amdgcn_mfma_f32_16x16x32_bf16(a[m], b[g], acc[g][m], 0, 0, 0);
    __syncthreads();
    cur ^= 1;
  }

  const int r0 = (lane >> 4) * 4, cl = lane & 15;
  const int hc = by * 32 + wn * 16 + cl;
  const float bi = bih[hc]        + bhh[hc];
  const float bf = bih[1024 + hc] + bhh[1024 + hc];
  const float bg = bih[2048 + hc] + bhh[2048 + hc];
  const float bo = bih[3072 + hc] + bhh[3072 + hc];
#pragma unroll
  for (int m = 0; m < 4; ++m)
#pragma unroll
    for (int j = 0; j < 4; ++j) {
      int row = bx * 128 + wm * 64 + m * 16 + r0 + j;
      u16x4 st = {f2bf(acc[0][m][j] + bi), f2bf(acc[1][m][j] + bf),
                  f2bf(acc[2][m][j] + bg), f2bf(acc[3][m][j] + bo)};
      xg4[(size_t)row * H_ + hc] = st;
    }
}

__global__ __launch_bounds__(256, 4) void k_step(
    const unsigned short* __restrict__ hprev, const unsigned short* __restrict__ whh,
    const u16x4* __restrict__ xg4, float* __restrict__ cbuf,
    unsigned short* __restrict__ hout) {
  __shared__ unsigned short As[2][128 * 32];
  __shared__ unsigned short Bs[2][128 * 32];
  const int tid = threadIdx.x, lane = tid & 63, wave = tid >> 6;
  const int bx = blockIdx.x, by = blockIdx.y;
  const int wm = wave >> 1, wn = wave & 1;
  const int rs = lane >> 2;
  const int c16 = (((lane & 3) ^ ((lane >> 3) & 3))) * 16;
  const int rdslot = ((lane >> 4) ^ ((lane >> 1) & 3)) * 8;

  const char* asrc0 = (const char*)hprev + ((size_t)(bx * 128 + (wave * 2 + 0) * 16 + rs) * H_) * 2 + c16;
  const char* asrc1 = (const char*)hprev + ((size_t)(bx * 128 + (wave * 2 + 1) * 16 + rs) * H_) * 2 + c16;
  const char* bsrc0 = (const char*)whh   + ((size_t)(wave * H_ + by * 32 +  0 + rs) * H_) * 2 + c16;
  const char* bsrc1 = (const char*)whh   + ((size_t)(wave * H_ + by * 32 + 16 + rs) * H_) * 2 + c16;

  f32x4 acc[4][4];
#pragma unroll
  for (int g = 0; g < 4; ++g)
#pragma unroll
    for (int m = 0; m < 4; ++m) acc[g][m] = {0.f, 0.f, 0.f, 0.f};

  gload_lds16(asrc0, &As[0][(wave * 2 + 0) * 512]);
  gload_lds16(asrc1, &As[0][(wave * 2 + 1) * 512]);
  gload_lds16(bsrc0, &Bs[0][(wave * 2 + 0) * 512]);
  gload_lds16(bsrc1, &Bs[0][(wave * 2 + 1) * 512]);
  __syncthreads();

  const int nt = H_ / 32;
  int cur = 0;
  for (int kk = 0; kk < nt; ++kk) {
    if (kk + 1 < nt) {
      const size_t kb = (size_t)(kk + 1) * 64;
      gload_lds16(asrc0 + kb, &As[cur ^ 1][(wave * 2 + 0) * 512]);
      gload_lds16(asrc1 + kb, &As[cur ^ 1][(wave * 2 + 1) * 512]);
      gload_lds16(bsrc0 + kb, &Bs[cur ^ 1][(wave * 2 + 0) * 512]);
      gload_lds16(bsrc1 + kb, &Bs[cur ^ 1][(wave * 2 + 1) * 512]);
    }
    bf16x8 a[4], b[4];
#pragma unroll
    for (int m = 0; m < 4; ++m)
      a[m] = *(const bf16x8*)&As[cur][(wm * 64 + m * 16 + (lane & 15)) * 32 + rdslot];
#pragma unroll
    for (int g = 0; g < 4; ++g)
      b[g] = *(const bf16x8*)&Bs[cur][((g * 2 + wn) * 16 + (lane & 15)) * 32 + rdslot];
#pragma unroll
    for (int g = 0; g < 4; ++g)
#pragma unroll
      for (int m = 0; m < 4; ++m)
        acc[g][m] = __builtin_amdgcn_mfma_f32_16x16x32_bf16(a[m], b[g], acc[g][m], 0, 0, 0);
    __syncthreads();
    cur ^= 1;
  }

  const int r0 = (lane >> 4) * 4, cl = lane & 15;
  const int hc = by * 32 + wn * 16 + cl;
#pragma unroll
  for (int m = 0; m < 4; ++m)
#pragma unroll
    for (int j = 0; j < 4; ++j) {
      int row = bx * 128 + wm * 64 + m * 16 + r0 + j;
      size_t ci = (size_t)row * H_ + hc;
      u16x4 xv = xg4[ci];
      float iv = sigmf(acc[0][m][j] + bf2f(xv[0]));
      float fv = sigmf(acc[1][m][j] + bf2f(xv[1]));
      float gv = tanh_fast(acc[2][m][j] + bf2f(xv[2]));
      float ov = sigmf(acc[3][m][j] + bf2f(xv[3]));
      float cv = fv * cbuf[ci] + iv * gv;
      cbuf[ci] = cv;
      hout[ci] = f2bf(ov * tanh_fast(cv));
    }
}

__global__ __launch_bounds__(256) void k_mlp(
    const unsigned short* __restrict__ h, const unsigned short* __restrict__ w1,
    const float* __restrict__ b1, const float* __restrict__ w2,
    const float* __restrict__ b2, float* __restrict__ delta, int t) {
  __shared__ unsigned short As[64 * 32];
  __shared__ unsigned short Bs[64 * 32];
  __shared__ float hid[64][65];
  const int tid = threadIdx.x, lane = tid & 63, wave = tid >> 6;
  const int bx = blockIdx.x;
  const int rs = lane >> 2;
  const int c16 = (((lane & 3) ^ ((lane >> 3) & 3))) * 16;
  const int rdslot = ((lane >> 4) ^ ((lane >> 1) & 3)) * 8;

  f32x4 acc[4];
#pragma unroll
  for (int n = 0; n < 4; ++n) acc[n] = {0.f, 0.f, 0.f, 0.f};

  for (int kk = 0; kk < H_ / 32; ++kk) {
    const int k0 = kk * 32;
    __syncthreads();
    {
      int row = bx * 64 + wave * 16 + rs;
      gload_lds16((const char*)h + ((size_t)row * H_ + k0) * 2 + c16,
                  (char*)As + wave * 1024);
    }
    {
      int jj = wave * 16 + rs;
      gload_lds16((const char*)w1 + ((size_t)jj * H_ + k0) * 2 + c16,
                  (char*)Bs + wave * 1024);
    }
    __syncthreads();
    bf16x8 a = *(const bf16x8*)&As[(wave * 16 + (lane & 15)) * 32 + rdslot];
#pragma unroll
    for (int n = 0; n < 4; ++n) {
      bf16x8 b = *(const bf16x8*)&Bs[(n * 16 + (lane & 15)) * 32 + rdslot];
      acc[n] = __builtin_amdgcn_mfma_f32_16x16x32_bf16(a, b, acc[n], 0, 0, 0);
    }
  }

  const int r0 = (lane >> 4) * 4, cl = lane & 15;
#pragma unroll
  for (int n = 0; n < 4; ++n)
#pragma unroll
    for (int j = 0; j < 4; ++j) {
      int row = wave * 16 + r0 + j;
      int col = n * 16 + cl;
      hid[row][col] = fmaxf(acc[n][j] + b1[col], 0.0f);
    }
  __syncthreads();

  if (tid < 128) {
    int r = tid >> 1, d = tid & 1;
    float s = b2[d];
#pragma unroll 8
    for (int k2 = 0; k2 < 64; ++k2) s += hid[r][k2] * w2[d * 64 + k2];
    delta[((size_t)(bx * 64 + r) * T_ + t) * 2 + d] = s;
  }
}

// ---------------- final cumsum over T + last_pos ----------------

__global__ void k_cumsum(const float* __restrict__ delta,
                         const float* __restrict__ lp, float* __restrict__ out) {
  int id = blockIdx.x * blockDim.x + threadIdx.x;
  if (id >= B_ * 2) return;
  int b = id >> 1, d = id & 1;
  float cum = lp[b * 2 + d];
  size_t base = (size_t)b * T_ * 2 + d;
  for (int t = 0; t < T_; ++t) {
    cum += delta[base + t * 2];
    out[base + t * 2] = cum;
  }
}

// ---------------- launch ----------------

extern "C" void kernel_launch(void* const* d_in, const int* in_sizes, int n_in,
                              void* d_out, int out_size, void* d_ws, size_t ws_size,
                              hipStream_t stream) {
  const float* z   = (const float*)d_in[0];
  const float* lv  = (const float*)d_in[1];
  const float* lp  = (const float*)d_in[2];
  const float* Wih = (const float*)d_in[3];
  const float* Whh = (const float*)d_in[4];
  const float* bih = (const float*)d_in[5];
  const float* bhh = (const float*)d_in[6];
  const float* W1  = (const float*)d_in[7];
  const float* b1  = (const float*)d_in[8];
  const float* W2  = (const float*)d_in[9];
  const float* b2  = (const float*)d_in[10];
  float* out = (float*)d_out;

  char* ws = (char*)d_ws;
  size_t off = 0;
  unsigned short* zaug   = (unsigned short*)(ws + off); off += (size_t)B_ * KA_ * 2;     //  8650752
  unsigned short* wih_bf = (unsigned short*)(ws + off); off += (size_t)G4_ * KA_ * 2;    //  8650752
  unsigned short* whh_bf = (unsigned short*)(ws + off); off += (size_t)G4_ * H_ * 2;     //  8388608
  unsigned short* w1_bf  = (unsigned short*)(ws + off); off += (size_t)MLPH_ * H_ * 2;   //   131072
  unsigned short* h_a    = (unsigned short*)(ws + off); off += (size_t)B_ * H_ * 2;      //  8388608
  unsigned short* h_b    = (unsigned short*)(ws + off); off += (size_t)B_ * H_ * 2;      //  8388608
  float*          delta  = (float*)(ws + off);          off += (size_t)B_ * T_ * 2 * 4;  //  1966080
  u16x4*          xg4    = (u16x4*)(ws + off);          off += (size_t)B_ * H_ * 8;      // 33554432 (fallback)
  float*          cbuf   = (float*)(ws + off);          off += (size_t)B_ * H_ * 4;      // 16777216 (fallback)
  // total ~94.9 MB

  const size_t BH = (size_t)B_ * H_;
  hipMemsetAsync(h_a, 0, BH * 2, stream);

  k_conv_bf16 <<<2048, 256, 0, stream>>>(Whh, whh_bf, G4_ * H_);
  k_conv_wih  <<<2048, 256, 0, stream>>>(Wih, wih_bf);
  k_build_zaug<<<2048, 256, 0, stream>>>(z, lp, lv, zaug);
  k_conv_bf16 <<<256, 256, 0, stream>>>(W1, w1_bf, MLPH_ * H_);

  void* kargs[] = {
    (void*)&zaug, (void*)&wih_bf, (void*)&whh_bf, (void*)&w1_bf,
    (void*)&bih, (void*)&bhh, (void*)&b1, (void*)&W2, (void*)&b2,
    (void*)&h_a, (void*)&h_b, (void*)&delta
  };
  hipError_t cerr = hipLaunchCooperativeKernel((const void*)k_persist, dim3(256),
                                               dim3(512), kargs, 0, stream);
  if (cerr != hipSuccess) {
    // validated round-4 fallback path
    hipMemsetAsync(cbuf, 0, BH * 4, stream);
    k_xgates<<<dim3(32, 32), 256, 0, stream>>>(zaug, wih_bf, bih, bhh, xg4);
    for (int t = 0; t < T_; ++t) {
      const unsigned short* hp = (t & 1) ? h_b : h_a;
      unsigned short*       hc = (t & 1) ? h_a : h_b;
      k_step<<<dim3(32, 32), 256, 0, stream>>>(hp, whh_bf, xg4, cbuf, hc);
      k_mlp <<<64, 256, 0, stream>>>(hc, w1_bf, b1, W2, b2, delta, t);
    }
  }

  k_cumsum<<<32, 256, 0, stream>>>(delta, lp, out);
}

// Round 10
// 3481.747 us; speedup vs baseline: 3.2181x; 3.2181x over previous
//
#include <hip/hip_runtime.h>
#include <stdint.h>

#define B_    4096
#define H_    1024
#define T_    60
#define IN_   1028
#define KA_   1056      // IN_ padded to multiple of 32
#define G4_   4096      // 4*H
#define MLPH_ 64
#define NB_   6         // MLP batch depth / h ring size

typedef __attribute__((ext_vector_type(8))) short bf16x8;
typedef __attribute__((ext_vector_type(4))) float f32x4;
typedef __attribute__((ext_vector_type(4))) unsigned short u16x4;

#define GLOBAL_AS __attribute__((address_space(1)))
#define LDS_AS    __attribute__((address_space(3)))

__device__ __forceinline__ void gload_lds16(const void* g, void* l) {
  __builtin_amdgcn_global_load_lds((GLOBAL_AS void*)const_cast<void*>(g),
                                   (LDS_AS void*)l, 16, 0, 0);
}

__device__ __forceinline__ unsigned short f2bf(float f) {
  union { float f; unsigned int u; } v; v.f = f;
  unsigned int r = v.u + 0x7FFFu + ((v.u >> 16) & 1u);
  return (unsigned short)(r >> 16);
}

__device__ __forceinline__ float bf2f(unsigned short u) {
  union { unsigned int u; float f; } v; v.u = ((unsigned int)u) << 16;
  return v.f;
}

__device__ __forceinline__ float sigmf(float x) {
  float e = __expf(-x);
  return __builtin_amdgcn_rcpf(1.0f + e);
}

__device__ __forceinline__ float tanh_fast(float x) {
  x = fminf(fmaxf(x, -15.0f), 15.0f);
  float e = __expf(2.0f * x);
  return (e - 1.0f) * __builtin_amdgcn_rcpf(e + 1.0f);
}

// ---------------- conversion / setup kernels ----------------

__global__ void k_conv_bf16(const float* __restrict__ src,
                            unsigned short* __restrict__ dst, int n) {
  int i = blockIdx.x * blockDim.x + threadIdx.x;
  int stride = gridDim.x * blockDim.x;
  for (; i < n; i += stride) dst[i] = f2bf(src[i]);
}

// W_ih (4096 x 1028) -> bf16 padded (4096 x 1056)
__global__ void k_conv_wih(const float* __restrict__ w,
                           unsigned short* __restrict__ dst) {
  int i = blockIdx.x * blockDim.x + threadIdx.x;
  int stride = gridDim.x * blockDim.x;
  const int n = G4_ * KA_;
  for (; i < n; i += stride) {
    int r = i / KA_, k = i - r * KA_;
    dst[i] = (k < IN_) ? f2bf(w[(size_t)r * IN_ + k]) : (unsigned short)0;
  }
}

// z_aug = [z | last_pos | last_vel | zero-pad]  (4096 x 1056 bf16)
__global__ void k_build_zaug(const float* __restrict__ z,
                             const float* __restrict__ lp,
                             const float* __restrict__ lv,
                             unsigned short* __restrict__ dst) {
  int i = blockIdx.x * blockDim.x + threadIdx.x;
  int stride = gridDim.x * blockDim.x;
  const int n = B_ * KA_;
  for (; i < n; i += stride) {
    int b = i / KA_, k = i - b * KA_;
    float v;
    if (k < H_)            v = z[(size_t)b * H_ + k];
    else if (k < H_ + 2)   v = lp[b * 2 + (k - H_)];
    else if (k < IN_)      v = lv[b * 2 + (k - H_ - 2)];
    else                   v = 0.0f;
    dst[i] = f2bf(v);
  }
}

// LDS layout (round-4 proven, 0 conflicts): chunk = 16 rows x 64B (1KB),
// staged by one wave: lane l -> row l>>2, linear slot l&3; global source slot
// pre-swizzled to (l&3)^((l>>3)&3), i.e. LDS[r][s] holds global chunk
// s ^ ((r>>1)&3). Fragment read: slot (lane>>4) ^ ((lane>>1)&3).

// ---------------- x_gates GEMM -> interleaved bf16x4 per (b, hc) ----------------
// (round-4 structure, runs once)

__global__ __launch_bounds__(256, 4) void k_xgates(
    const unsigned short* __restrict__ zaug, const unsigned short* __restrict__ wih,
    const float* __restrict__ bih, const float* __restrict__ bhh,
    u16x4* __restrict__ xg4) {
  __shared__ unsigned short As[2][128 * 32];
  __shared__ unsigned short Bs[2][128 * 32];
  const int tid = threadIdx.x, lane = tid & 63, wave = tid >> 6;
  const int bx = blockIdx.x, by = blockIdx.y;
  const int wm = wave >> 1, wn = wave & 1;
  const int rs = lane >> 2;
  const int c16 = (((lane & 3) ^ ((lane >> 3) & 3))) * 16;
  const int rdslot = ((lane >> 4) ^ ((lane >> 1) & 3)) * 8;

  const char* asrc0 = (const char*)zaug + ((size_t)(bx * 128 + (wave * 2 + 0) * 16 + rs) * KA_) * 2 + c16;
  const char* asrc1 = (const char*)zaug + ((size_t)(bx * 128 + (wave * 2 + 1) * 16 + rs) * KA_) * 2 + c16;
  const char* bsrc0 = (const char*)wih  + ((size_t)(wave * H_ + by * 32 +  0 + rs) * KA_) * 2 + c16;
  const char* bsrc1 = (const char*)wih  + ((size_t)(wave * H_ + by * 32 + 16 + rs) * KA_) * 2 + c16;

  f32x4 acc[4][4];   // [gate][m]
#pragma unroll
  for (int g = 0; g < 4; ++g)
#pragma unroll
    for (int m = 0; m < 4; ++m) acc[g][m] = {0.f, 0.f, 0.f, 0.f};

  gload_lds16(asrc0, &As[0][(wave * 2 + 0) * 512]);
  gload_lds16(asrc1, &As[0][(wave * 2 + 1) * 512]);
  gload_lds16(bsrc0, &Bs[0][(wave * 2 + 0) * 512]);
  gload_lds16(bsrc1, &Bs[0][(wave * 2 + 1) * 512]);
  __syncthreads();

  const int nt = KA_ / 32;
  int cur = 0;
  for (int kk = 0; kk < nt; ++kk) {
    if (kk + 1 < nt) {
      const size_t kb = (size_t)(kk + 1) * 64;
      gload_lds16(asrc0 + kb, &As[cur ^ 1][(wave * 2 + 0) * 512]);
      gload_lds16(asrc1 + kb, &As[cur ^ 1][(wave * 2 + 1) * 512]);
      gload_lds16(bsrc0 + kb, &Bs[cur ^ 1][(wave * 2 + 0) * 512]);
      gload_lds16(bsrc1 + kb, &Bs[cur ^ 1][(wave * 2 + 1) * 512]);
    }
    bf16x8 a[4], b[4];
#pragma unroll
    for (int m = 0; m < 4; ++m)
      a[m] = *(const bf16x8*)&As[cur][(wm * 64 + m * 16 + (lane & 15)) * 32 + rdslot];
#pragma unroll
    for (int g = 0; g < 4; ++g)
      b[g] = *(const bf16x8*)&Bs[cur][((g * 2 + wn) * 16 + (lane & 15)) * 32 + rdslot];
#pragma unroll
    for (int g = 0; g < 4; ++g)
#pragma unroll
      for (int m = 0; m < 4; ++m)
        acc[g][m] = __builtin_amdgcn_mfma_f32_16x16x32_bf16(a[m], b[g], acc[g][m], 0, 0, 0);
    __syncthreads();
    cur ^= 1;
  }

  const int r0 = (lane >> 4) * 4, cl = lane & 15;
  const int hc = by * 32 + wn * 16 + cl;
  const float bi = bih[hc]        + bhh[hc];
  const float bf = bih[1024 + hc] + bhh[1024 + hc];
  const float bg = bih[2048 + hc] + bhh[2048 + hc];
  const float bo = bih[3072 + hc] + bhh[3072 + hc];
#pragma unroll
  for (int m = 0; m < 4; ++m)
#pragma unroll
    for (int j = 0; j < 4; ++j) {
      int row = bx * 128 + wm * 64 + m * 16 + r0 + j;
      u16x4 st = {f2bf(acc[0][m][j] + bi), f2bf(acc[1][m][j] + bf),
                  f2bf(acc[2][m][j] + bg), f2bf(acc[3][m][j] + bo)};
      xg4[(size_t)row * H_ + hc] = st;
    }
}

// ---------------- LSTM step: retiled for LDS-traffic reduction ----------------
// Block = 128 rows x 64 hc x 4 gates (grid 512, 1D, XCD-pinned by-mapping).
// 4 waves (wm rows-half, wn hc-half); wave = 64 rows x 32 hc x 4 gates:
// A-frags 4, B-frags 8 -> 12 ds_reads per 32 MFMA (0.375 KB/16-MFMA vs
// round-4's 0.5). LDS: A 2x8KB + B 2x16KB = 48 KB; 2-buf + syncthreads
// (round-4 proven schedule). XCD pin: by = (id&7)*2 + ((id>>3)&1) keeps each
// XCD's 1 MB W_hh slice L2-resident for all 60 steps.

__global__ __launch_bounds__(256, 2) void k_step(
    const unsigned short* __restrict__ hprev, const unsigned short* __restrict__ whh,
    const u16x4* __restrict__ xg4, float* __restrict__ cbuf,
    unsigned short* __restrict__ hout) {
  __shared__ unsigned short As[2][128 * 32];   //  8 KB per buf
  __shared__ unsigned short Bs[2][256 * 32];   // 16 KB per buf
  const int tid = threadIdx.x, lane = tid & 63, wave = tid >> 6;
  const int id = blockIdx.x;
  const int sl = id >> 3;
  const int by = (id & 7) * 2 + (sl & 1);   // hc-tile [0,16), XCD-pinned
  const int bx = sl >> 1;                   // row-tile [0,32)
  const int wm = wave >> 1, wn = wave & 1;
  const int rs = lane >> 2;
  const int cl = lane & 15;
  const int c16 = ((lane & 3) ^ ((lane >> 3) & 3)) * 16;
  const int rdslot = ((lane >> 4) ^ ((lane >> 1) & 3)) * 8;

  // A staging: wave stages chunks {2w, 2w+1} (16 rows each)
  const char* a0 = (const char*)hprev + ((size_t)(bx * 128 + (wave * 2 + 0) * 16 + rs) * H_) * 2 + c16;
  const char* a1 = (const char*)hprev + ((size_t)(bx * 128 + (wave * 2 + 1) * 16 + rs) * H_) * 2 + c16;
  // B staging: wave stages chunks {4w..4w+3}; tile row ch*16+rs -> gate ch>>2,
  // hc-local (ch&3)*16+rs
  const char* bsrc[4];
#pragma unroll
  for (int i = 0; i < 4; ++i) {
    int ch = wave * 4 + i;
    int row = (ch >> 2) * H_ + by * 64 + (ch & 3) * 16 + rs;
    bsrc[i] = (const char*)whh + (size_t)row * (H_ * 2) + c16;
  }

  auto stage = [&](int kt, int bu) {
    const size_t kb = (size_t)kt * 64;
    gload_lds16(a0 + kb, &As[bu][(wave * 2 + 0) * 512]);
    gload_lds16(a1 + kb, &As[bu][(wave * 2 + 1) * 512]);
#pragma unroll
    for (int i = 0; i < 4; ++i)
      gload_lds16(bsrc[i] + kb, &Bs[bu][(wave * 4 + i) * 512]);
  };

  f32x4 acc[4][2][4];   // [gate][hc16][m]
#pragma unroll
  for (int g = 0; g < 4; ++g)
#pragma unroll
    for (int n = 0; n < 2; ++n)
#pragma unroll
      for (int m = 0; m < 4; ++m) acc[g][n][m] = {0.f, 0.f, 0.f, 0.f};

  stage(0, 0);
  __syncthreads();

  const int nt = H_ / 32;
  for (int kk = 0; kk < nt; ++kk) {
    const int cur = kk & 1;
    if (kk + 1 < nt) stage(kk + 1, cur ^ 1);
    const unsigned short* Ab = As[cur];
    const unsigned short* Bb = Bs[cur];
    bf16x8 a[4], b[4];
#pragma unroll
    for (int m = 0; m < 4; ++m)
      a[m] = *(const bf16x8*)&Ab[(wm * 64 + m * 16 + cl) * 32 + rdslot];
#pragma unroll
    for (int n = 0; n < 2; ++n) {
#pragma unroll
      for (int g = 0; g < 4; ++g)
        b[g] = *(const bf16x8*)&Bb[(g * 64 + wn * 32 + n * 16 + cl) * 32 + rdslot];
#pragma unroll
      for (int g = 0; g < 4; ++g)
#pragma unroll
        for (int m = 0; m < 4; ++m)
          acc[g][n][m] = __builtin_amdgcn_mfma_f32_16x16x32_bf16(a[m], b[g], acc[g][n][m], 0, 0, 0);
    }
    __syncthreads();
  }

  const int r0 = (lane >> 4) * 4;
#pragma unroll
  for (int m = 0; m < 4; ++m)
#pragma unroll
    for (int j = 0; j < 4; ++j) {
      int row = bx * 128 + wm * 64 + m * 16 + r0 + j;
#pragma unroll
      for (int n = 0; n < 2; ++n) {
        int hc = by * 64 + wn * 32 + n * 16 + cl;
        size_t ci = (size_t)row * H_ + hc;
        u16x4 xv = xg4[ci];
        float iv = sigmf(acc[0][n][m][j] + bf2f(xv[0]));
        float fv = sigmf(acc[1][n][m][j] + bf2f(xv[1]));
        float gv = tanh_fast(acc[2][n][m][j] + bf2f(xv[2]));
        float ov = sigmf(acc[3][n][m][j] + bf2f(xv[3]));
        float cv = fv * cbuf[ci] + iv * gv;
        cbuf[ci] = cv;
        hout[ci] = f2bf(ov * tanh_fast(cv));
      }
    }
}

// ---------------- batched MLP over NB_ steps ----------------

__global__ __launch_bounds__(256) void k_mlp(
    const unsigned short* __restrict__ hring, const unsigned short* __restrict__ w1,
    const float* __restrict__ b1, const float* __restrict__ w2,
    const float* __restrict__ b2, float* __restrict__ delta, int t0) {
  __shared__ unsigned short As[64 * 32];
  __shared__ unsigned short Bs[64 * 32];
  __shared__ float hid[64][65];
  const int tid = threadIdx.x, lane = tid & 63, wave = tid >> 6;
  const int bx = blockIdx.x;
  const unsigned short* h = hring + (size_t)blockIdx.y * B_ * H_;
  const int t = t0 + blockIdx.y;
  const int rs = lane >> 2;
  const int c16 = (((lane & 3) ^ ((lane >> 3) & 3))) * 16;
  const int rdslot = ((lane >> 4) ^ ((lane >> 1) & 3)) * 8;

  f32x4 acc[4];
#pragma unroll
  for (int n = 0; n < 4; ++n) acc[n] = {0.f, 0.f, 0.f, 0.f};

  for (int kk = 0; kk < H_ / 32; ++kk) {
    const int k0 = kk * 32;
    __syncthreads();
    {
      int row = bx * 64 + wave * 16 + rs;
      gload_lds16((const char*)h + ((size_t)row * H_ + k0) * 2 + c16,
                  (char*)As + wave * 1024);
    }
    {
      int jj = wave * 16 + rs;
      gload_lds16((const char*)w1 + ((size_t)jj * H_ + k0) * 2 + c16,
                  (char*)Bs + wave * 1024);
    }
    __syncthreads();
    bf16x8 a = *(const bf16x8*)&As[(wave * 16 + (lane & 15)) * 32 + rdslot];
#pragma unroll
    for (int n = 0; n < 4; ++n) {
      bf16x8 b = *(const bf16x8*)&Bs[(n * 16 + (lane & 15)) * 32 + rdslot];
      acc[n] = __builtin_amdgcn_mfma_f32_16x16x32_bf16(a, b, acc[n], 0, 0, 0);
    }
  }

  const int r0 = (lane >> 4) * 4, cl = lane & 15;
#pragma unroll
  for (int n = 0; n < 4; ++n)
#pragma unroll
    for (int j = 0; j < 4; ++j) {
      int row = wave * 16 + r0 + j;     // local row 0..63
      int col = n * 16 + cl;            // hidden unit 0..63
      hid[row][col] = fmaxf(acc[n][j] + b1[col], 0.0f);
    }
  __syncthreads();

  if (tid < 128) {
    int r = tid >> 1, d = tid & 1;
    float s = b2[d];
#pragma unroll 8
    for (int k2 = 0; k2 < 64; ++k2) s += hid[r][k2] * w2[d * 64 + k2];
    delta[((size_t)(bx * 64 + r) * T_ + t) * 2 + d] = s;
  }
}

// ---------------- final cumsum over T + last_pos ----------------

__global__ void k_cumsum(const float* __restrict__ delta,
                         const float* __restrict__ lp, float* __restrict__ out) {
  int id = blockIdx.x * blockDim.x + threadIdx.x;
  if (id >= B_ * 2) return;
  int b = id >> 1, d = id & 1;
  float cum = lp[b * 2 + d];
  size_t base = (size_t)b * T_ * 2 + d;
  for (int t = 0; t < T_; ++t) {
    cum += delta[base + t * 2];
    out[base + t * 2] = cum;
  }
}

// ---------------- launch ----------------

extern "C" void kernel_launch(void* const* d_in, const int* in_sizes, int n_in,
                              void* d_out, int out_size, void* d_ws, size_t ws_size,
                              hipStream_t stream) {
  const float* z   = (const float*)d_in[0];
  const float* lv  = (const float*)d_in[1];
  const float* lp  = (const float*)d_in[2];
  const float* Wih = (const float*)d_in[3];
  const float* Whh = (const float*)d_in[4];
  const float* bih = (const float*)d_in[5];
  const float* bhh = (const float*)d_in[6];
  const float* W1  = (const float*)d_in[7];
  const float* b1  = (const float*)d_in[8];
  const float* W2  = (const float*)d_in[9];
  const float* b2  = (const float*)d_in[10];
  float* out = (float*)d_out;

  char* ws = (char*)d_ws;
  size_t off = 0;
  u16x4*          xg4    = (u16x4*)(ws + off);          off += (size_t)B_ * H_ * 8;       // 33554432
  unsigned short* whh_bf = (unsigned short*)(ws + off); off += (size_t)G4_ * H_ * 2;      //  8388608
  unsigned short* wih_bf = (unsigned short*)(ws + off); off += (size_t)G4_ * KA_ * 2;     //  8650752
  unsigned short* zaug   = (unsigned short*)(ws + off); off += (size_t)B_ * KA_ * 2;      //  8650752
  unsigned short* w1_bf  = (unsigned short*)(ws + off); off += (size_t)MLPH_ * H_ * 2;    //   131072
  unsigned short* hring  = (unsigned short*)(ws + off); off += (size_t)NB_ * B_ * H_ * 2; // 50331648
  float*          cbuf   = (float*)(ws + off);          off += (size_t)B_ * H_ * 4;       // 16777216
  float*          delta  = (float*)(ws + off);          off += (size_t)B_ * T_ * 2 * 4;   //  1966080
  // total 128450560 bytes

  const size_t BH = (size_t)B_ * H_;

  // zero c and the h(-1) slot (= slot NB_-1 of the ring)
  hipMemsetAsync(hring + (NB_ - 1) * BH, 0, BH * 2, stream);
  hipMemsetAsync(cbuf, 0, BH * 4, stream);

  k_conv_bf16 <<<2048, 256, 0, stream>>>(Whh, whh_bf, G4_ * H_);
  k_conv_wih  <<<2048, 256, 0, stream>>>(Wih, wih_bf);
  k_build_zaug<<<2048, 256, 0, stream>>>(z, lp, lv, zaug);
  k_conv_bf16 <<<256, 256, 0, stream>>>(W1, w1_bf, MLPH_ * H_);

  k_xgates<<<dim3(32, 32), 256, 0, stream>>>(zaug, wih_bf, bih, bhh, xg4);

  for (int t = 0; t < T_; ++t) {
    const unsigned short* hp = hring + (size_t)((t + NB_ - 1) % NB_) * BH;
    unsigned short*       hc = hring + (size_t)(t % NB_) * BH;
    k_step<<<512, 256, 0, stream>>>(hp, whh_bf, xg4, cbuf, hc);
    if ((t % NB_) == NB_ - 1)
      k_mlp<<<dim3(64, NB_), 256, 0, stream>>>(hring, w1_bf, b1, W2, b2, delta, t - (NB_ - 1));
  }

  k_cumsum<<<32, 256, 0, stream>>>(delta, lp, out);
}

// Round 11
// 3393.859 us; speedup vs baseline: 3.3014x; 1.0259x over previous
//
#include <hip/hip_runtime.h>
#include <stdint.h>

#define B_    4096
#define H_    1024
#define T_    60
#define IN_   1028
#define KA_   1056      // IN_ padded to multiple of 32
#define G4_   4096      // 4*H
#define MLPH_ 64
#define NB_   6         // MLP batch depth / h ring size

typedef __attribute__((ext_vector_type(8))) short bf16x8;
typedef __attribute__((ext_vector_type(4))) float f32x4;
typedef __attribute__((ext_vector_type(4))) unsigned short u16x4;

#define GLOBAL_AS __attribute__((address_space(1)))
#define LDS_AS    __attribute__((address_space(3)))

__device__ __forceinline__ void gload_lds16(const void* g, void* l) {
  __builtin_amdgcn_global_load_lds((GLOBAL_AS void*)const_cast<void*>(g),
                                   (LDS_AS void*)l, 16, 0, 0);
}

__device__ __forceinline__ unsigned short f2bf(float f) {
  union { float f; unsigned int u; } v; v.f = f;
  unsigned int r = v.u + 0x7FFFu + ((v.u >> 16) & 1u);
  return (unsigned short)(r >> 16);
}

__device__ __forceinline__ float bf2f(unsigned short u) {
  union { unsigned int u; float f; } v; v.u = ((unsigned int)u) << 16;
  return v.f;
}

__device__ __forceinline__ float sigmf(float x) {
  float e = __expf(-x);
  return __builtin_amdgcn_rcpf(1.0f + e);
}

__device__ __forceinline__ float tanh_fast(float x) {
  x = fminf(fmaxf(x, -15.0f), 15.0f);
  float e = __expf(2.0f * x);
  return (e - 1.0f) * __builtin_amdgcn_rcpf(e + 1.0f);
}

// ---------------- conversion / setup kernels ----------------

__global__ void k_conv_bf16(const float* __restrict__ src,
                            unsigned short* __restrict__ dst, int n) {
  int i = blockIdx.x * blockDim.x + threadIdx.x;
  int stride = gridDim.x * blockDim.x;
  for (; i < n; i += stride) dst[i] = f2bf(src[i]);
}

// W_ih (4096 x 1028) -> bf16 padded (4096 x 1056)
__global__ void k_conv_wih(const float* __restrict__ w,
                           unsigned short* __restrict__ dst) {
  int i = blockIdx.x * blockDim.x + threadIdx.x;
  int stride = gridDim.x * blockDim.x;
  const int n = G4_ * KA_;
  for (; i < n; i += stride) {
    int r = i / KA_, k = i - r * KA_;
    dst[i] = (k < IN_) ? f2bf(w[(size_t)r * IN_ + k]) : (unsigned short)0;
  }
}

// z_aug = [z | last_pos | last_vel | zero-pad]  (4096 x 1056 bf16)
__global__ void k_build_zaug(const float* __restrict__ z,
                             const float* __restrict__ lp,
                             const float* __restrict__ lv,
                             unsigned short* __restrict__ dst) {
  int i = blockIdx.x * blockDim.x + threadIdx.x;
  int stride = gridDim.x * blockDim.x;
  const int n = B_ * KA_;
  for (; i < n; i += stride) {
    int b = i / KA_, k = i - b * KA_;
    float v;
    if (k < H_)            v = z[(size_t)b * H_ + k];
    else if (k < H_ + 2)   v = lp[b * 2 + (k - H_)];
    else if (k < IN_)      v = lv[b * 2 + (k - H_ - 2)];
    else                   v = 0.0f;
    dst[i] = f2bf(v);
  }
}

// LDS layout (round-4 proven, 0 conflicts): chunk = 16 rows x 64B (1KB),
// staged by one wave: lane l -> row l>>2, linear slot l&3; global source slot
// pre-swizzled to (l&3)^((l>>3)&3). Fragment read slot: (lane>>4)^((lane>>1)&3).

// ---------------- x_gates GEMM -> interleaved bf16x4 per (b, hc) ----------------
// (round-4 structure, runs once)

__global__ __launch_bounds__(256, 4) void k_xgates(
    const unsigned short* __restrict__ zaug, const unsigned short* __restrict__ wih,
    const float* __restrict__ bih, const float* __restrict__ bhh,
    u16x4* __restrict__ xg4) {
  __shared__ unsigned short As[2][128 * 32];
  __shared__ unsigned short Bs[2][128 * 32];
  const int tid = threadIdx.x, lane = tid & 63, wave = tid >> 6;
  const int bx = blockIdx.x, by = blockIdx.y;
  const int wm = wave >> 1, wn = wave & 1;
  const int rs = lane >> 2;
  const int c16 = (((lane & 3) ^ ((lane >> 3) & 3))) * 16;
  const int rdslot = ((lane >> 4) ^ ((lane >> 1) & 3)) * 8;

  const char* asrc0 = (const char*)zaug + ((size_t)(bx * 128 + (wave * 2 + 0) * 16 + rs) * KA_) * 2 + c16;
  const char* asrc1 = (const char*)zaug + ((size_t)(bx * 128 + (wave * 2 + 1) * 16 + rs) * KA_) * 2 + c16;
  const char* bsrc0 = (const char*)wih  + ((size_t)(wave * H_ + by * 32 +  0 + rs) * KA_) * 2 + c16;
  const char* bsrc1 = (const char*)wih  + ((size_t)(wave * H_ + by * 32 + 16 + rs) * KA_) * 2 + c16;

  f32x4 acc[4][4];   // [gate][m]
#pragma unroll
  for (int g = 0; g < 4; ++g)
#pragma unroll
    for (int m = 0; m < 4; ++m) acc[g][m] = {0.f, 0.f, 0.f, 0.f};

  gload_lds16(asrc0, &As[0][(wave * 2 + 0) * 512]);
  gload_lds16(asrc1, &As[0][(wave * 2 + 1) * 512]);
  gload_lds16(bsrc0, &Bs[0][(wave * 2 + 0) * 512]);
  gload_lds16(bsrc1, &Bs[0][(wave * 2 + 1) * 512]);
  __syncthreads();

  const int nt = KA_ / 32;
  int cur = 0;
  for (int kk = 0; kk < nt; ++kk) {
    if (kk + 1 < nt) {
      const size_t kb = (size_t)(kk + 1) * 64;
      gload_lds16(asrc0 + kb, &As[cur ^ 1][(wave * 2 + 0) * 512]);
      gload_lds16(asrc1 + kb, &As[cur ^ 1][(wave * 2 + 1) * 512]);
      gload_lds16(bsrc0 + kb, &Bs[cur ^ 1][(wave * 2 + 0) * 512]);
      gload_lds16(bsrc1 + kb, &Bs[cur ^ 1][(wave * 2 + 1) * 512]);
    }
    bf16x8 a[4], b[4];
#pragma unroll
    for (int m = 0; m < 4; ++m)
      a[m] = *(const bf16x8*)&As[cur][(wm * 64 + m * 16 + (lane & 15)) * 32 + rdslot];
#pragma unroll
    for (int g = 0; g < 4; ++g)
      b[g] = *(const bf16x8*)&Bs[cur][((g * 2 + wn) * 16 + (lane & 15)) * 32 + rdslot];
#pragma unroll
    for (int g = 0; g < 4; ++g)
#pragma unroll
      for (int m = 0; m < 4; ++m)
        acc[g][m] = __builtin_amdgcn_mfma_f32_16x16x32_bf16(a[m], b[g], acc[g][m], 0, 0, 0);
    __syncthreads();
    cur ^= 1;
  }

  const int r0 = (lane >> 4) * 4, cl = lane & 15;
  const int hc = by * 32 + wn * 16 + cl;
  const float bi = bih[hc]        + bhh[hc];
  const float bf = bih[1024 + hc] + bhh[1024 + hc];
  const float bg = bih[2048 + hc] + bhh[2048 + hc];
  const float bo = bih[3072 + hc] + bhh[3072 + hc];
#pragma unroll
  for (int m = 0; m < 4; ++m)
#pragma unroll
    for (int j = 0; j < 4; ++j) {
      int row = bx * 128 + wm * 64 + m * 16 + r0 + j;
      u16x4 st = {f2bf(acc[0][m][j] + bi), f2bf(acc[1][m][j] + bf),
                  f2bf(acc[2][m][j] + bg), f2bf(acc[3][m][j] + bo)};
      xg4[(size_t)row * H_ + hc] = st;
    }
}

// ---------------- LSTM step: round-4 geometry + 3-buf counted vmcnt ----------------
// Identical tile/wave/swizzle/reads/epilogue to the proven 48.8us kernel; only
// the sync structure changes: 3-buffer ring (48 KB), 2-tile prefetch lead,
// s_waitcnt vmcnt(8/4/0) + raw s_barrier pair per K-tile (T4: never drain the
// just-issued stage). Ledger (4 gloads/tile/wave): prologue t0,t1 = 8 out;
// iter kt stages kt+2 (->12), vmcnt(8) retires tile kt; kt=30 -> vmcnt(4);
// kt=31 -> vmcnt(0). Stage at iter kt+1 overwrites the buffer read at iter kt
// -- ordered by the trailing barrier (reads are lgkm-retired before each
// wave's MFMA issue, hence before its barrier arrival).

__global__ __launch_bounds__(256, 3) void k_step(
    const unsigned short* __restrict__ hprev, const unsigned short* __restrict__ whh,
    const u16x4* __restrict__ xg4, float* __restrict__ cbuf,
    unsigned short* __restrict__ hout) {
  __shared__ unsigned short As[3][128 * 32];
  __shared__ unsigned short Bs[3][128 * 32];
  const int tid = threadIdx.x, lane = tid & 63, wave = tid >> 6;
  const int bx = blockIdx.x, by = blockIdx.y;
  const int wm = wave >> 1, wn = wave & 1;
  const int rs = lane >> 2;
  const int c16 = (((lane & 3) ^ ((lane >> 3) & 3))) * 16;
  const int rdslot = ((lane >> 4) ^ ((lane >> 1) & 3)) * 8;

  const char* asrc0 = (const char*)hprev + ((size_t)(bx * 128 + (wave * 2 + 0) * 16 + rs) * H_) * 2 + c16;
  const char* asrc1 = (const char*)hprev + ((size_t)(bx * 128 + (wave * 2 + 1) * 16 + rs) * H_) * 2 + c16;
  const char* bsrc0 = (const char*)whh   + ((size_t)(wave * H_ + by * 32 +  0 + rs) * H_) * 2 + c16;
  const char* bsrc1 = (const char*)whh   + ((size_t)(wave * H_ + by * 32 + 16 + rs) * H_) * 2 + c16;

  f32x4 acc[4][4];   // [gate][m]
#pragma unroll
  for (int g = 0; g < 4; ++g)
#pragma unroll
    for (int m = 0; m < 4; ++m) acc[g][m] = {0.f, 0.f, 0.f, 0.f};

  auto stage = [&](int kt, int bu) {
    const size_t kb = (size_t)kt * 64;
    gload_lds16(asrc0 + kb, &As[bu][(wave * 2 + 0) * 512]);
    gload_lds16(asrc1 + kb, &As[bu][(wave * 2 + 1) * 512]);
    gload_lds16(bsrc0 + kb, &Bs[bu][(wave * 2 + 0) * 512]);
    gload_lds16(bsrc1 + kb, &Bs[bu][(wave * 2 + 1) * 512]);
  };

  // prologue: tiles 0,1 -> bufs 0,1 (8 loads/wave in flight)
  stage(0, 0);
  stage(1, 1);

  const int nt = H_ / 32;   // 32
  int cur = 0;
  for (int kk = 0; kk < nt; ++kk) {
    if (kk + 2 < nt) {
      int nb = cur + 2; if (nb >= 3) nb -= 3;
      stage(kk + 2, nb);
      asm volatile("s_waitcnt vmcnt(8)" ::: "memory");
    } else if (kk + 1 < nt) {
      asm volatile("s_waitcnt vmcnt(4)" ::: "memory");
    } else {
      asm volatile("s_waitcnt vmcnt(0)" ::: "memory");
    }
    __builtin_amdgcn_s_barrier();

    bf16x8 a[4], b[4];
#pragma unroll
    for (int m = 0; m < 4; ++m)
      a[m] = *(const bf16x8*)&As[cur][(wm * 64 + m * 16 + (lane & 15)) * 32 + rdslot];
#pragma unroll
    for (int g = 0; g < 4; ++g)
      b[g] = *(const bf16x8*)&Bs[cur][((g * 2 + wn) * 16 + (lane & 15)) * 32 + rdslot];
#pragma unroll
    for (int g = 0; g < 4; ++g)
#pragma unroll
      for (int m = 0; m < 4; ++m)
        acc[g][m] = __builtin_amdgcn_mfma_f32_16x16x32_bf16(a[m], b[g], acc[g][m], 0, 0, 0);

    __builtin_amdgcn_s_barrier();
    ++cur; if (cur == 3) cur = 0;
  }

  const int r0 = (lane >> 4) * 4, cl = lane & 15;
  const int hc = by * 32 + wn * 16 + cl;
#pragma unroll
  for (int m = 0; m < 4; ++m)
#pragma unroll
    for (int j = 0; j < 4; ++j) {
      int row = bx * 128 + wm * 64 + m * 16 + r0 + j;   // batch index
      size_t ci = (size_t)row * H_ + hc;
      u16x4 xv = xg4[ci];
      float iv = sigmf(acc[0][m][j] + bf2f(xv[0]));
      float fv = sigmf(acc[1][m][j] + bf2f(xv[1]));
      float gv = tanh_fast(acc[2][m][j] + bf2f(xv[2]));
      float ov = sigmf(acc[3][m][j] + bf2f(xv[3]));
      float cv = fv * cbuf[ci] + iv * gv;
      cbuf[ci] = cv;
      hout[ci] = f2bf(ov * tanh_fast(cv));
    }
}

// ---------------- batched MLP over NB_ steps ----------------

__global__ __launch_bounds__(256) void k_mlp(
    const unsigned short* __restrict__ hring, const unsigned short* __restrict__ w1,
    const float* __restrict__ b1, const float* __restrict__ w2,
    const float* __restrict__ b2, float* __restrict__ delta, int t0) {
  __shared__ unsigned short As[64 * 32];
  __shared__ unsigned short Bs[64 * 32];
  __shared__ float hid[64][65];
  const int tid = threadIdx.x, lane = tid & 63, wave = tid >> 6;
  const int bx = blockIdx.x;
  const unsigned short* h = hring + (size_t)blockIdx.y * B_ * H_;
  const int t = t0 + blockIdx.y;
  const int rs = lane >> 2;
  const int c16 = (((lane & 3) ^ ((lane >> 3) & 3))) * 16;
  const int rdslot = ((lane >> 4) ^ ((lane >> 1) & 3)) * 8;

  f32x4 acc[4];
#pragma unroll
  for (int n = 0; n < 4; ++n) acc[n] = {0.f, 0.f, 0.f, 0.f};

  for (int kk = 0; kk < H_ / 32; ++kk) {
    const int k0 = kk * 32;
    __syncthreads();
    {
      int row = bx * 64 + wave * 16 + rs;
      gload_lds16((const char*)h + ((size_t)row * H_ + k0) * 2 + c16,
                  (char*)As + wave * 1024);
    }
    {
      int jj = wave * 16 + rs;
      gload_lds16((const char*)w1 + ((size_t)jj * H_ + k0) * 2 + c16,
                  (char*)Bs + wave * 1024);
    }
    __syncthreads();
    bf16x8 a = *(const bf16x8*)&As[(wave * 16 + (lane & 15)) * 32 + rdslot];
#pragma unroll
    for (int n = 0; n < 4; ++n) {
      bf16x8 b = *(const bf16x8*)&Bs[(n * 16 + (lane & 15)) * 32 + rdslot];
      acc[n] = __builtin_amdgcn_mfma_f32_16x16x32_bf16(a, b, acc[n], 0, 0, 0);
    }
  }

  const int r0 = (lane >> 4) * 4, cl = lane & 15;
#pragma unroll
  for (int n = 0; n < 4; ++n)
#pragma unroll
    for (int j = 0; j < 4; ++j) {
      int row = wave * 16 + r0 + j;     // local row 0..63
      int col = n * 16 + cl;            // hidden unit 0..63
      hid[row][col] = fmaxf(acc[n][j] + b1[col], 0.0f);
    }
  __syncthreads();

  if (tid < 128) {
    int r = tid >> 1, d = tid & 1;
    float s = b2[d];
#pragma unroll 8
    for (int k2 = 0; k2 < 64; ++k2) s += hid[r][k2] * w2[d * 64 + k2];
    delta[((size_t)(bx * 64 + r) * T_ + t) * 2 + d] = s;
  }
}

// ---------------- final cumsum over T + last_pos ----------------

__global__ void k_cumsum(const float* __restrict__ delta,
                         const float* __restrict__ lp, float* __restrict__ out) {
  int id = blockIdx.x * blockDim.x + threadIdx.x;
  if (id >= B_ * 2) return;
  int b = id >> 1, d = id & 1;
  float cum = lp[b * 2 + d];
  size_t base = (size_t)b * T_ * 2 + d;
  for (int t = 0; t < T_; ++t) {
    cum += delta[base + t * 2];
    out[base + t * 2] = cum;
  }
}

// ---------------- launch ----------------

extern "C" void kernel_launch(void* const* d_in, const int* in_sizes, int n_in,
                              void* d_out, int out_size, void* d_ws, size_t ws_size,
                              hipStream_t stream) {
  const float* z   = (const float*)d_in[0];
  const float* lv  = (const float*)d_in[1];
  const float* lp  = (const float*)d_in[2];
  const float* Wih = (const float*)d_in[3];
  const float* Whh = (const float*)d_in[4];
  const float* bih = (const float*)d_in[5];
  const float* bhh = (const float*)d_in[6];
  const float* W1  = (const float*)d_in[7];
  const float* b1  = (const float*)d_in[8];
  const float* W2  = (const float*)d_in[9];
  const float* b2  = (const float*)d_in[10];
  float* out = (float*)d_out;

  char* ws = (char*)d_ws;
  size_t off = 0;
  u16x4*          xg4    = (u16x4*)(ws + off);          off += (size_t)B_ * H_ * 8;       // 33554432
  unsigned short* whh_bf = (unsigned short*)(ws + off); off += (size_t)G4_ * H_ * 2;      //  8388608
  unsigned short* wih_bf = (unsigned short*)(ws + off); off += (size_t)G4_ * KA_ * 2;     //  8650752
  unsigned short* zaug   = (unsigned short*)(ws + off); off += (size_t)B_ * KA_ * 2;      //  8650752
  unsigned short* w1_bf  = (unsigned short*)(ws + off); off += (size_t)MLPH_ * H_ * 2;    //   131072
  unsigned short* hring  = (unsigned short*)(ws + off); off += (size_t)NB_ * B_ * H_ * 2; // 50331648
  float*          cbuf   = (float*)(ws + off);          off += (size_t)B_ * H_ * 4;       // 16777216
  float*          delta  = (float*)(ws + off);          off += (size_t)B_ * T_ * 2 * 4;   //  1966080
  // total 128450560 bytes

  const size_t BH = (size_t)B_ * H_;

  // zero c and the h(-1) slot (= slot NB_-1 of the ring)
  hipMemsetAsync(hring + (NB_ - 1) * BH, 0, BH * 2, stream);
  hipMemsetAsync(cbuf, 0, BH * 4, stream);

  k_conv_bf16 <<<2048, 256, 0, stream>>>(Whh, whh_bf, G4_ * H_);
  k_conv_wih  <<<2048, 256, 0, stream>>>(Wih, wih_bf);
  k_build_zaug<<<2048, 256, 0, stream>>>(z, lp, lv, zaug);
  k_conv_bf16 <<<256, 256, 0, stream>>>(W1, w1_bf, MLPH_ * H_);

  k_xgates<<<dim3(32, 32), 256, 0, stream>>>(zaug, wih_bf, bih, bhh, xg4);

  for (int t = 0; t < T_; ++t) {
    const unsigned short* hp = hring + (size_t)((t + NB_ - 1) % NB_) * BH;
    unsigned short*       hc = hring + (size_t)(t % NB_) * BH;
    k_step<<<dim3(32, 32), 256, 0, stream>>>(hp, whh_bf, xg4, cbuf, hc);
    if ((t % NB_) == NB_ - 1)
      k_mlp<<<dim3(64, NB_), 256, 0, stream>>>(hring, w1_bf, b1, W2, b2, delta, t - (NB_ - 1));
  }

  k_cumsum<<<32, 256, 0, stream>>>(delta, lp, out);
}